// Round 2
// baseline (4951.645 us; speedup 1.0000x reference)
//
#include <hip/hip_runtime.h>
#include <hip/hip_bf16.h>
#include <math.h>

#define VOCAB  32000
#define EMBED  256
#define HIDDEN 512
#define BATCH  64
#define TCAP   32
#define SEQ    33      // T_CAP + 1
#define G4     2048    // 4 * HIDDEN

typedef unsigned short ushort_t;

__device__ __forceinline__ float bf2f(ushort_t u) {
    union { unsigned int i; float f; } v;
    v.i = ((unsigned int)u) << 16;
    return v.f;
}

__device__ __forceinline__ void bfpair(unsigned int u, float& lo, float& hi) {
    union { unsigned int i; float f; } a, b;
    a.i = u << 16;
    b.i = u & 0xffff0000u;
    lo = a.f; hi = b.f;
}

// load 8 consecutive weights (either dtype) as fp32
template<bool BF>
__device__ __forceinline__ void ldw8(const void* p, size_t idx, float* w) {
    if constexpr (BF) {
        uint4 u = *(const uint4*)((const ushort_t*)p + idx);
        bfpair(u.x, w[0], w[1]); bfpair(u.y, w[2], w[3]);
        bfpair(u.z, w[4], w[5]); bfpair(u.w, w[6], w[7]);
    } else {
        float4 a = *(const float4*)((const float*)p + idx);
        float4 b = *(const float4*)((const float*)p + idx + 4);
        w[0]=a.x; w[1]=a.y; w[2]=a.z; w[3]=a.w;
        w[4]=b.x; w[5]=b.y; w[6]=b.z; w[7]=b.w;
    }
}

template<bool BF>
__device__ __forceinline__ float ldw1(const void* p, size_t i) {
    if constexpr (BF) return bf2f(((const ushort_t*)p)[i]);
    else return ((const float*)p)[i];
}

__device__ __forceinline__ float dot8f(const float* w, const float* h) {
    return w[0]*h[0]+w[1]*h[1]+w[2]*h[2]+w[3]*h[3]
         + w[4]*h[4]+w[5]*h[5]+w[6]*h[6]+w[7]*h[7];
}

__device__ __forceinline__ float sigm(float x) { return 1.0f / (1.0f + expf(-x)); }

// ---------------------------------------------------------------------------
// Dtype detector: low 16 bits of each fp32-word of `features`.
// bf16 data -> low half is a bf16 ~N(0,1): exponent in [113,131] nearly always.
// fp32 data -> low half is random mantissa bits: exponent uniform, ~7% hit.
// 8192 words is within bounds for both worlds (bf16 buffer = exactly 32KB).
// ---------------------------------------------------------------------------
__global__ void k_detect(const unsigned int* __restrict__ w, int* __restrict__ mode) {
    __shared__ int cnt[256];
    int c = 0;
    for (int i = threadIdx.x; i < 8192; i += 256) {
        unsigned int lo = w[i] & 0xffffu;
        int e = (lo >> 7) & 0xff;
        if (e >= 113 && e <= 131) c++;
    }
    cnt[threadIdx.x] = c;
    __syncthreads();
    for (int s = 128; s > 0; s >>= 1) {
        if (threadIdx.x < s) cnt[threadIdx.x] += cnt[threadIdx.x + s];
        __syncthreads();
    }
    if (threadIdx.x == 0) *mode = (cnt[0] > 6000) ? 1 : 0;   // 1 = bf16
}

// ---------------------------------------------------------------------------
// K1: xp[bt][g] = dot(x_bt, W_ih[g]) + b_ih[g] + b_hh[g]
// grid (8, 2112), block 256.
// ---------------------------------------------------------------------------
template<bool BF>
__global__ void k_xproj(const int* __restrict__ mode,
                        const void* __restrict__ features,
                        const int*  __restrict__ captions,
                        const void* __restrict__ embedding,
                        const void* __restrict__ W_ih,
                        const void* __restrict__ b_ih,
                        const void* __restrict__ b_hh,
                        float* __restrict__ xp) {
    if (*mode != (int)BF) return;
    __shared__ float xs[EMBED];
    int bt  = blockIdx.y;
    int b   = bt / SEQ;
    int t   = bt % SEQ;
    int tid = threadIdx.x;

    size_t src_off;
    const void* src;
    if (t == 0) { src = features;  src_off = (size_t)b * EMBED; }
    else        { src = embedding; src_off = (size_t)captions[b * TCAP + (t - 1)] * EMBED; }
    xs[tid] = ldw1<BF>(src, src_off + tid);
    __syncthreads();

    int g = blockIdx.x * 256 + tid;
    float acc = ldw1<BF>(b_ih, g) + ldw1<BF>(b_hh, g);
    size_t wbase = (size_t)g * EMBED;
    for (int e = 0; e < EMBED; e += 8) {
        float w[8];
        ldw8<BF>(W_ih, wbase + e, w);
        acc += dot8f(w, xs + e);
    }
    xp[(size_t)bt * G4 + g] = acc;
}

// ---------------------------------------------------------------------------
// K2: one LSTM step. grid (8, 16), block 256 = 64 j-lanes x 4 batches.
// Thread (jl, bb) computes all 4 gates for (b = by*4+bb, j = bx*64+jl).
// h_prev read from hs[t-1] (read-only this launch) -> race-free.
// c_buf[b][j] owned by exactly one thread per launch.
// ---------------------------------------------------------------------------
template<bool BF>
__global__ void k_step(const int* __restrict__ mode,
                       const float* __restrict__ xp,
                       const void* __restrict__ W_hh,
                       float* __restrict__ c_buf,
                       float* __restrict__ hs,
                       int t) {
    if (*mode != (int)BF) return;
    __shared__ float hsh[4][HIDDEN];
    int tid = threadIdx.x;
    int jl  = tid & 63, bb = tid >> 6;
    int j   = blockIdx.x * 64 + jl;
    int b   = blockIdx.y * 4 + bb;

    if (t > 0) {
        // stage h_prev for the 4 batches: 2048 floats, 2 float4/thread
        for (int r = 0; r < 2; r++) {
            int i4 = tid + r * 256;            // 0..511 float4 slots
            int sb = i4 >> 7, k4 = (i4 & 127) << 2;
            *(float4*)(&hsh[sb][k4]) =
                *(const float4*)(hs + ((size_t)(blockIdx.y * 4 + sb) * SEQ + (t - 1)) * HIDDEN + k4);
        }
        __syncthreads();
    }

    size_t xbase = ((size_t)b * SEQ + t) * G4;
    float ai = xp[xbase + j];
    float af = xp[xbase + HIDDEN + j];
    float ag = xp[xbase + 2 * HIDDEN + j];
    float ao = xp[xbase + 3 * HIDDEN + j];

    if (t > 0) {
        const float* hp = hsh[bb];
        size_t r0 = (size_t)j * HIDDEN;
        size_t r1 = (size_t)(HIDDEN + j) * HIDDEN;
        size_t r2 = (size_t)(2 * HIDDEN + j) * HIDDEN;
        size_t r3 = (size_t)(3 * HIDDEN + j) * HIDDEN;
        for (int k = 0; k < HIDDEN; k += 8) {
            float w[8];
            ldw8<BF>(W_hh, r0 + k, w); ai += dot8f(w, hp + k);
            ldw8<BF>(W_hh, r1 + k, w); af += dot8f(w, hp + k);
            ldw8<BF>(W_hh, r2 + k, w); ag += dot8f(w, hp + k);
            ldw8<BF>(W_hh, r3 + k, w); ao += dot8f(w, hp + k);
        }
    }

    float c_prev = (t > 0) ? c_buf[b * HIDDEN + j] : 0.0f;
    float c = sigm(af) * c_prev + sigm(ai) * tanhf(ag);
    float h = sigm(ao) * tanhf(c);
    c_buf[b * HIDDEN + j] = c;
    hs[((size_t)b * SEQ + t) * HIDDEN + j] = h;
}

// ---------------------------------------------------------------------------
// K3: logits = hs @ W_out^T + b_out. M=2112, N=32000, K=512.
// grid (125, 66), block 256. Thread: one n, 32 m rows (register-blocked).
// hs addresses are wave-uniform -> scalar loads; W_out re-read 66x (L3-hot).
// ---------------------------------------------------------------------------
#define MT 32
template<bool BF>
__global__ void k_logits(const int* __restrict__ mode,
                         const float* __restrict__ hs,
                         const void* __restrict__ W_out,
                         const void* __restrict__ b_out,
                         void* __restrict__ out) {
    if (*mode != (int)BF) return;
    int n  = blockIdx.x * 256 + threadIdx.x;
    int m0 = blockIdx.y * MT;

    float bias = ldw1<BF>(b_out, n);
    float acc[MT];
#pragma unroll
    for (int m = 0; m < MT; m++) acc[m] = bias;

    size_t wbase = (size_t)n * HIDDEN;
    for (int k = 0; k < HIDDEN; k += 8) {
        float w[8];
        ldw8<BF>(W_out, wbase + k, w);
#pragma unroll
        for (int m = 0; m < MT; m++) {
            const float* hrow = hs + (size_t)(m0 + m) * HIDDEN;   // uniform addr
            acc[m] += dot8f(w, hrow + k);
        }
    }

#pragma unroll
    for (int m = 0; m < MT; m++) {
        size_t o = (size_t)(m0 + m) * VOCAB + n;
        if constexpr (BF) ((__hip_bfloat16*)out)[o] = __float2bfloat16(acc[m]);
        else              ((float*)out)[o] = acc[m];
    }
}

// ---------------------------------------------------------------------------
extern "C" void kernel_launch(void* const* d_in, const int* in_sizes, int n_in,
                              void* d_out, int out_size, void* d_ws, size_t ws_size,
                              hipStream_t stream) {
    const void* features  = d_in[0];
    const int*  captions  = (const int*)d_in[1];
    const void* embedding = d_in[3];
    const void* W_ih      = d_in[4];
    const void* W_hh      = d_in[5];
    const void* b_ih      = d_in[6];
    const void* b_hh      = d_in[7];
    const void* W_out     = d_in[8];
    const void* b_out     = d_in[9];

    // ws: xp[2112][2048] f32 | hs[2112][512] f32 | c_buf[64][512] f32 | mode
    char* ws = (char*)d_ws;
    float* xp    = (float*)ws;
    float* hs    = (float*)(ws + (size_t)2112 * G4 * 4);
    float* c_buf = (float*)(ws + (size_t)2112 * G4 * 4 + (size_t)2112 * HIDDEN * 4);
    int*   mode  = (int*)(ws + (size_t)2112 * G4 * 4 + (size_t)2112 * HIDDEN * 4
                             + (size_t)BATCH * HIDDEN * 4);

    k_detect<<<1, 256, 0, stream>>>((const unsigned int*)features, mode);

    k_xproj<false><<<dim3(8, BATCH * SEQ), 256, 0, stream>>>(
        mode, features, captions, embedding, W_ih, b_ih, b_hh, xp);
    k_xproj<true><<<dim3(8, BATCH * SEQ), 256, 0, stream>>>(
        mode, features, captions, embedding, W_ih, b_ih, b_hh, xp);

    for (int t = 0; t < SEQ; t++) {
        k_step<false><<<dim3(8, BATCH / 4), 256, 0, stream>>>(mode, xp, W_hh, c_buf, hs, t);
        k_step<true><<<dim3(8, BATCH / 4), 256, 0, stream>>>(mode, xp, W_hh, c_buf, hs, t);
    }

    k_logits<false><<<dim3(VOCAB / 256, (BATCH * SEQ) / MT), 256, 0, stream>>>(
        mode, hs, W_out, b_out, d_out);
    k_logits<true><<<dim3(VOCAB / 256, (BATCH * SEQ) / MT), 256, 0, stream>>>(
        mode, hs, W_out, b_out, d_out);
}